// Round 7
// baseline (6058.929 us; speedup 1.0000x reference)
//
#include <hip/hip_runtime.h>

// Problem constants
#define TT 512
#define BB 256
#define II 128
#define HH 256
#define CC 10

typedef __attribute__((ext_vector_type(8))) _Float16 f16x8;
typedef __attribute__((ext_vector_type(4))) _Float16 f16x4;
typedef __attribute__((ext_vector_type(4))) float    f32x4;

#define SELLO 0x05040100u
#define SELHI 0x07060302u

__device__ __forceinline__ float fsig(float x){ return 1.0f/(1.0f+__expf(-x)); }
__device__ __forceinline__ float ftanh(float x){ return 2.0f/(1.0f+__expf(-2.0f*x)) - 1.0f; }

// Relaxed RMW poll at the coherence point (cold path only — backpressure).
__device__ __forceinline__ unsigned cpoll(unsigned* p){
  return __hip_atomic_fetch_add(p, 0u, __ATOMIC_RELAXED, __HIP_MEMORY_SCOPE_AGENT);
}
__device__ __forceinline__ unsigned poll_until(unsigned* p, unsigned tgt){
  unsigned v = 0;
  if((threadIdx.x & 63) == 0){
    v = cpoll(p);
    while(v < tgt){ __builtin_amdgcn_s_sleep(1); v = cpoll(p); }
  }
  unsigned u = __builtin_amdgcn_readfirstlane(v);
  asm volatile("" ::: "memory");
  return u;
}

// Two 16B IF$-coherent loads (sc0 sc1 bypass L1/L2: ring lines are reused
// across steps; stale private-cache copies are never invalidated remotely).
__device__ __forceinline__ void ld2(const unsigned* p, uint4& a, uint4& b){
  asm volatile("global_load_dwordx4 %0, %2, off sc0 sc1\n\t"
               "global_load_dwordx4 %1, %2, off offset:16 sc0 sc1"
               : "=&v"(a), "=&v"(b) : "v"(p) : "memory");
}
// 16B sc load straight into an fp16 A-fragment (L0 x path; no tags needed).
__device__ __forceinline__ f16x8 ld1h(const _Float16* p){
  f16x8 r;
  asm volatile("global_load_dwordx4 %0, %1, off sc0 sc1" : "=v"(r) : "v"(p) : "memory");
  return r;
}
__device__ __forceinline__ void waitv0 (){ asm volatile("s_waitcnt vmcnt(0)"  ::: "memory"); }
__device__ __forceinline__ void waitv4 (){ asm volatile("s_waitcnt vmcnt(4)"  ::: "memory"); }
__device__ __forceinline__ void waitv16(){ asm volatile("s_waitcnt vmcnt(16)" ::: "memory"); }
// Pins: 32-bit tied operands only. NOTE: macro parameter must NOT be named
// x/y/z/w — R6 failed because (x).x substituted the member too.
#define PIN4(vv) asm volatile("" : "+v"((vv).x), "+v"((vv).y), "+v"((vv).z), "+v"((vv).w))
#define PINH(vv) asm volatile("" : "+v"(vv))

// Tagged u32 = (step_tag16 << 16) | h_fp16_bits. A 4B store is single-copy
// atomic -> tag+payload never tear; the store IS the arrival signal.
__device__ __forceinline__ void store_u32(unsigned* p, unsigned w){
  asm volatile("global_store_dword %0, %1, off sc0 sc1" :: "v"(p), "v"(w) : "memory");
}
__device__ __forceinline__ unsigned tagbad(const uint4& a, unsigned dup){
  return (__builtin_amdgcn_perm(a.y, a.x, SELHI) ^ dup)
       | (__builtin_amdgcn_perm(a.w, a.z, SELHI) ^ dup);
}
__device__ __forceinline__ f16x8 extr8(const uint4& a, const uint4& b){
  union { unsigned d[4]; f16x8 v; } r;
  r.d[0] = __builtin_amdgcn_perm(a.y, a.x, SELLO);
  r.d[1] = __builtin_amdgcn_perm(a.w, a.z, SELLO);
  r.d[2] = __builtin_amdgcn_perm(b.y, b.x, SELLO);
  r.d[3] = __builtin_amdgcn_perm(b.w, b.z, SELLO);
  return r.v;
}

// One WAVE owns 16 samples x 16 units x all 4 gates (D: row=quad*4+r,
// col=l15; A-frag m=l15, k=quad*8+e — R2..R4-verified). Weights fp16,
// register-resident. All hot sync is tag-in-word via IF$; the only counter
// is the cold L0<-L1 backpressure.
template<bool IS_L1>
__device__ __forceinline__ void run_wave(
    const _Float16* __restrict__ xc,    // L0 only: [B][T][I] fp16
    unsigned* __restrict__ ring0,       // tagged [4][B][H]: L0 h out; L0 rec in; L1 x in
    const _Float16* __restrict__ Wh, const _Float16* __restrict__ Wx,
    const float* __restrict__ b_ih, const float* __restrict__ b_hh,
    const int* __restrict__ lengths,
    unsigned* __restrict__ ring1,       // tagged [2][B][H]: L1 recurrent
    float* __restrict__ hT,
    unsigned* __restrict__ ctrX, int gb, int gj)
{
  constexpr int KXT = IS_L1 ? 8 : 4;
  const int lane = threadIdx.x & 63;
  const int quad = lane >> 4;
  const int l15  = lane & 15;
  const int koff = quad << 3;
  const int b0   = gb << 4;
  const int u    = (gj << 4) + l15;
  const size_t arow = (size_t)(b0 + l15);

  // Stationary weight fragments: B[k][n] = W[g*H+u][k]
  f16x8 wh[4][8], wx[4][KXT];
  float bias[4];
#pragma unroll
  for(int g=0; g<4; ++g){
    const int row = g*HH + u;
#pragma unroll
    for(int kt=0; kt<8; ++kt){
      wh[g][kt] = *(const f16x8*)(Wh + (size_t)row*HH + kt*32 + koff);
      PINH(wh[g][kt]);
    }
#pragma unroll
    for(int kt=0; kt<KXT; ++kt){
      wx[g][kt] = *(const f16x8*)(Wx + (size_t)row*(KXT*32) + kt*32 + koff);
      PINH(wx[g][kt]);
    }
    bias[g] = b_ih[row] + b_hh[row];
  }

  int sb[4], len[4]; float cs[4], hs[4];
#pragma unroll
  for(int r=0; r<4; ++r){
    sb[r]  = b0 + (quad<<2) + r;
    len[r] = lengths[sb[r]];
    cs[r] = 0.f; hs[r] = 0.f;
  }

  unsigned bp = 0;          // cached backpressure (L0)
  f16x8 ax[KXT];

  // ---- acquire x_0 ----
  if(IS_L1){
    uint4 xr[16];
    const unsigned* xp = ring0 + arow*HH + koff;    // slot 0, tag 1
#pragma unroll
    for(int kt=0; kt<8; ++kt) ld2(xp + kt*32, xr[2*kt], xr[2*kt+1]);
    const unsigned dupx = 1u | (1u<<16);
    for(;;){
      waitv0();
#pragma unroll
      for(int i=0; i<16; ++i) PIN4(xr[i]);
      unsigned bad = 0;
#pragma unroll
      for(int i=0; i<16; ++i) bad |= tagbad(xr[i], dupx);
      if(__all(bad == 0)) break;
#pragma unroll
      for(int kt=0; kt<8; ++kt) ld2(xp + kt*32, xr[2*kt], xr[2*kt+1]);
    }
    if(lane == 0)
      __hip_atomic_fetch_add(ctrX, 1u, __ATOMIC_RELAXED, __HIP_MEMORY_SCOPE_AGENT);
#pragma unroll
    for(int kt=0; kt<8; ++kt) ax[kt] = extr8(xr[2*kt], xr[2*kt+1]);
  } else {
    const _Float16* xp = xc + (arow*TT + 0)*II + koff;
#pragma unroll
    for(int kt=0; kt<KXT; ++kt) ax[kt] = ld1h(xp + kt*32);
  }

  for(int s=0; s<TT; ++s){
    // ---- 1) issue h[s-1] tagged loads (the one critical IF$ round trip)
    uint4 hr[16];
    const int rslot = IS_L1 ? ((s-1)&1) : ((s-1)&3);
    const unsigned* hp = (IS_L1 ? ring1 : ring0)
                       + ((size_t)rslot*BB + arow)*HH + koff;
    if(s > 0){
#pragma unroll
      for(int kt=0; kt<8; ++kt) ld2(hp + kt*32, hr[2*kt], hr[2*kt+1]);
    }

    // ---- 2) x-MFMAs under the h latency
    if(!IS_L1){
      if(s > 0) waitv16(); else waitv0();   // drain only the 4 ax loads
#pragma unroll
      for(int kt=0; kt<KXT; ++kt) PINH(ax[kt]);
    }
    f32x4 acc[4];
#pragma unroll
    for(int g=0; g<4; ++g) acc[g] = (f32x4){bias[g],bias[g],bias[g],bias[g]};
#pragma unroll
    for(int kt=0; kt<KXT; ++kt)
#pragma unroll
      for(int g=0; g<4; ++g)
        acc[g] = __builtin_amdgcn_mfma_f32_16x16x32_f16(ax[kt], wx[g][kt], acc[g], 0,0,0);

    // ---- 3) h tag-check (spin-reload), extract, h-MFMAs
    uint4 xr[16];
    bool xr_live = false;
    if(s > 0){
      const unsigned dup = (unsigned)s | ((unsigned)s << 16);
      for(;;){
        waitv0();
#pragma unroll
        for(int i=0; i<16; ++i) PIN4(hr[i]);
        unsigned bad = 0;
#pragma unroll
        for(int i=0; i<16; ++i) bad |= tagbad(hr[i], dup);
        if(__all(bad == 0)) break;
#pragma unroll
        for(int kt=0; kt<8; ++kt) ld2(hp + kt*32, hr[2*kt], hr[2*kt+1]);
      }
      f16x8 ah[8];
#pragma unroll
      for(int kt=0; kt<8; ++kt) ah[kt] = extr8(hr[2*kt], hr[2*kt+1]);

      // issue next-x loads now (hr dead): round trip overlaps MFMA+elementwise
      if(IS_L1 && s+1 < TT){
        const unsigned* xp = ring0 + ((size_t)((s+1)&3)*BB + arow)*HH + koff;
#pragma unroll
        for(int kt=0; kt<8; ++kt) ld2(xp + kt*32, xr[2*kt], xr[2*kt+1]);
        xr_live = true;
      }
#pragma unroll
      for(int kt=0; kt<8; ++kt)
#pragma unroll
        for(int g=0; g<4; ++g)
          acc[g] = __builtin_amdgcn_mfma_f32_16x16x32_f16(ah[kt], wh[g][kt], acc[g], 0,0,0);
    } else if(IS_L1){
      const unsigned* xp = ring0 + ((size_t)1*BB + arow)*HH + koff;  // slot 1
#pragma unroll
      for(int kt=0; kt<8; ++kt) ld2(xp + kt*32, xr[2*kt], xr[2*kt+1]);
      xr_live = true;
    }

    // ---- 4) elementwise
    unsigned hw[4];
#pragma unroll
    for(int r=0; r<4; ++r){
      float iv = fsig (acc[0][r]);
      float fv = fsig (acc[1][r]);
      float gv = ftanh(acc[2][r]);
      float ov = fsig (acc[3][r]);
      float cn = fv*cs[r] + iv*gv;
      float hn = ov*ftanh(cn);
      if(s < len[r]){ cs[r] = cn; hs[r] = hn; }    // freeze past length
      _Float16 hf = (_Float16)hs[r];
      hw[r] = (unsigned)__builtin_bit_cast(unsigned short, hf);
    }

    // ---- 5) L0 backpressure (cold): don't overwrite x L1 hasn't consumed
    if(!IS_L1 && s >= 4){
      const unsigned tgt = 16u*(unsigned)(s-3);
      if(bp < tgt) bp = poll_until(ctrX, tgt);
    }

    // ---- 6) tagged h stores (store == arrival)
    {
      const int wslot = IS_L1 ? (s&1) : (s&3);
      const unsigned tw = ((unsigned)(s+1)) << 16;
      unsigned* op = (IS_L1 ? ring1 : ring0) + (size_t)wslot*BB*HH + u;
#pragma unroll
      for(int r=0; r<4; ++r)
        store_u32(op + (size_t)sb[r]*HH, tw | hw[r]);
    }
    if(IS_L1 && s == TT-1){
#pragma unroll
      for(int r=0; r<4; ++r) hT[(size_t)sb[r]*HH + u] = hs[r];
    }

    // ---- 7) validate + extract next x
    if(s+1 < TT){
      if(IS_L1){
        const unsigned* xp = ring0 + ((size_t)((s+1)&3)*BB + arow)*HH + koff;
        const unsigned dupx = (unsigned)(s+2) | ((unsigned)(s+2) << 16);
        if(!xr_live){   // unreachable structurally, but keep the compiler honest
#pragma unroll
          for(int kt=0; kt<8; ++kt) ld2(xp + kt*32, xr[2*kt], xr[2*kt+1]);
        }
        bool first = true;
        for(;;){
          if(first) waitv4(); else waitv0();   // first pass: let h-stores fly
          first = false;
#pragma unroll
          for(int i=0; i<16; ++i) PIN4(xr[i]);
          unsigned bad = 0;
#pragma unroll
          for(int i=0; i<16; ++i) bad |= tagbad(xr[i], dupx);
          if(__all(bad == 0)) break;
#pragma unroll
          for(int kt=0; kt<8; ++kt) ld2(xp + kt*32, xr[2*kt], xr[2*kt+1]);
        }
        if(lane == 0)
          __hip_atomic_fetch_add(ctrX, 1u, __ATOMIC_RELAXED, __HIP_MEMORY_SCOPE_AGENT);
#pragma unroll
        for(int kt=0; kt<8; ++kt) ax[kt] = extr8(xr[2*kt], xr[2*kt+1]);
      } else {
        const _Float16* xp = xc + (arow*TT + (s+1))*II + koff;
#pragma unroll
        for(int kt=0; kt<KXT; ++kt) ax[kt] = ld1h(xp + kt*32);
      }
    }
  }
}

// 512 single-wave WGs: layer = blk>>8, gb = blk&15, gj = (blk>>4)&15.
// blk%8 swizzle co-locates a group's waves on an XCD under round-robin
// dispatch (locality heuristic; correctness is via IF$-scope ops).
__global__ __launch_bounds__(64, 1)
void lstm_fused(const _Float16* __restrict__ xc,
                const _Float16* __restrict__ Wh0, const _Float16* __restrict__ Wx0,
                const _Float16* __restrict__ Wh1, const _Float16* __restrict__ Wx1,
                const float* __restrict__ b_ih0, const float* __restrict__ b_hh0,
                const float* __restrict__ b_ih1, const float* __restrict__ b_hh1,
                const int* __restrict__ lens,
                unsigned* __restrict__ ring0, unsigned* __restrict__ ring1,
                float* __restrict__ hT, unsigned* __restrict__ ctr)
{
  const int blk   = blockIdx.x;
  const int layer = blk >> 8;
  const int gb    = blk & 15;
  const int gj    = (blk >> 4) & 15;
  unsigned* cx = ctr + gb*32;            // 128B-padded backpressure counter
  if(layer == 0){
    run_wave<false>(xc, ring0, Wh0, Wx0, b_ih0, b_hh0, lens,
                    nullptr, nullptr, cx, gb, gj);
  } else {
    run_wave<true >(nullptr, ring0, Wh1, Wx1, b_ih1, b_hh1, lens,
                    ring1, hT, cx, gb, gj);
  }
}

// fp32 -> fp16 elementwise convert (vectorized x4)
__global__ __launch_bounds__(256)
void cvt4(const float* __restrict__ in, _Float16* __restrict__ out, int n4)
{
  int i = blockIdx.x*256 + threadIdx.x;
  if(i < n4){
    float4 v = ((const float4*)in)[i];
    f16x4 o;
    o[0]=(_Float16)v.x; o[1]=(_Float16)v.y; o[2]=(_Float16)v.z; o[3]=(_Float16)v.w;
    ((f16x4*)out)[i] = o;
  }
}

// logits = hT @ W_fc^T + b_fc ; softmax over 10 classes. One wave per sample.
__global__ __launch_bounds__(64)
void fc_softmax(const float* __restrict__ hT,
                const float* __restrict__ W_fc,
                const float* __restrict__ b_fc,
                float* __restrict__ out)
{
  const int b = blockIdx.x;
  const int lane = threadIdx.x;
  float p[CC];
#pragma unroll
  for (int c = 0; c < CC; ++c) p[c] = 0.f;
  const float* hb = hT + b * HH;
  for (int k = lane; k < HH; k += 64){
    float hv = hb[k];
#pragma unroll
    for (int c = 0; c < CC; ++c) p[c] += hv * W_fc[c * HH + k];
  }
#pragma unroll
  for (int c = 0; c < CC; ++c){
#pragma unroll
    for (int off = 32; off > 0; off >>= 1) p[c] += __shfl_down(p[c], off);
  }
  if (lane == 0){
    float m = -1e30f;
#pragma unroll
    for (int c = 0; c < CC; ++c){ p[c] += b_fc[c]; m = fmaxf(m, p[c]); }
    float ssum = 0.f;
#pragma unroll
    for (int c = 0; c < CC; ++c){ p[c] = __expf(p[c] - m); ssum += p[c]; }
    float inv = 1.0f / ssum;
#pragma unroll
    for (int c = 0; c < CC; ++c) out[b * CC + c] = p[c] * inv;
  }
}

extern "C" void kernel_launch(void* const* d_in, const int* in_sizes, int n_in,
                              void* d_out, int out_size, void* d_ws, size_t ws_size,
                              hipStream_t stream) {
  const float* x      = (const float*)d_in[0];   // [B][T][I]
  const int*   lens   = (const int*)  d_in[1];   // [B]
  const float* W_fc   = (const float*)d_in[2];   // [C][H]
  const float* b_fc   = (const float*)d_in[3];   // [C]
  const float* W_ih0  = (const float*)d_in[4];   // [4H][I]
  const float* W_hh0  = (const float*)d_in[5];   // [4H][H]
  const float* b_ih0  = (const float*)d_in[6];
  const float* b_hh0  = (const float*)d_in[7];
  const float* W_ih1  = (const float*)d_in[8];   // [4H][H]
  const float* W_hh1  = (const float*)d_in[9];
  const float* b_ih1  = (const float*)d_in[10];
  const float* b_hh1  = (const float*)d_in[11];
  float* out = (float*)d_out;

  char* ws = (char*)d_ws;
  // ws layout (bytes):
  //   [0, 8K)            backpressure counters (16 x 128B)
  //   [8192, +1M)        ring0 u32 [4][B][H]   (L0 h out / L0 rec / L1 x)
  //   [1056768, +512K)   ring1 u32 [2][B][H]   (L1 recurrent)
  //   [1581056, +256K)   hT fp32
  //   [1843200 ..)       fp16 weights: Wh0 512K, Wx0 256K, Wh1 512K, Wx1 512K
  //   [3678208, +32M)    xc fp16 [B][T][I]        total ~35.5 MB
  unsigned* ctr   = (unsigned*)ws;
  unsigned* ring0 = (unsigned*)(ws + 8192);
  unsigned* ring1 = (unsigned*)(ws + 1056768);
  float*    hT    = (float*)(ws + 1581056);
  _Float16* Wh0c  = (_Float16*)(ws + 1843200);
  _Float16* Wx0c  = (_Float16*)(ws + 2367488);
  _Float16* Wh1c  = (_Float16*)(ws + 2629632);
  _Float16* Wx1c  = (_Float16*)(ws + 3153920);
  _Float16* xc    = (_Float16*)(ws + 3678208);

  // zero counters + rings (tag 0 != any step tag 1..512; ws is re-poisoned
  // 0xAA before every timed launch, so rings MUST be cleared here)
  (void)hipMemsetAsync(ws, 0, 1581056, stream);

  // prep: fp32 -> fp16 (weights + x)
  cvt4<<<dim3((BB*TT*II/4 + 255)/256), dim3(256), 0, stream>>>(x,     xc,   BB*TT*II/4);
  cvt4<<<dim3((4*HH*HH/4  + 255)/256), dim3(256), 0, stream>>>(W_hh0, Wh0c, 4*HH*HH/4);
  cvt4<<<dim3((4*HH*II/4  + 255)/256), dim3(256), 0, stream>>>(W_ih0, Wx0c, 4*HH*II/4);
  cvt4<<<dim3((4*HH*HH/4  + 255)/256), dim3(256), 0, stream>>>(W_hh1, Wh1c, 4*HH*HH/4);
  cvt4<<<dim3((4*HH*HH/4  + 255)/256), dim3(256), 0, stream>>>(W_ih1, Wx1c, 4*HH*HH/4);

  lstm_fused<<<dim3(512), dim3(64), 0, stream>>>(
      xc, Wh0c, Wx0c, Wh1c, Wx1c, b_ih0, b_hh0, b_ih1, b_hh1, lens,
      ring0, ring1, hT, ctr);

  fc_softmax<<<dim3(BB), dim3(64), 0, stream>>>(hT, W_fc, b_fc, out);
}